// Round 21
// baseline (1055.615 us; speedup 1.0000x reference)
//
#include <hip/hip_runtime.h>
#include <hip/hip_bf16.h>

// ---------------------------------------------------------------------------
// DynamiSE: enc+hw fused GEMM -> CSR build -> fused (gather + dopri5) ODE.
// Round 21: front-end trim.
//   r20: total 1043 = ODE 755 (gather fused, anchor) + ~288 front-end.
//   Biggest term: enc_hw staged 64KB weights per 4-ROW block -> 800MB of
//   weight reads. Fix: 64 rows/block (16x inner loop, weights staged once)
//   -> 50MB. Also fuse the two fill launches into one (fill_both).
//   ODE kernel byte-identical to r20.
// ---------------------------------------------------------------------------

typedef __attribute__((ext_vector_type(8))) short short8v;   // 8 bf16 = 4 VGPR
typedef __attribute__((ext_vector_type(4))) float f32x4;
typedef __attribute__((ext_vector_type(2))) unsigned uint2v;

__device__ __forceinline__ float fast_tanh(float x) {
    float e = __builtin_amdgcn_exp2f(x * 2.8853900817779268f);
    return 1.0f - 2.0f * __builtin_amdgcn_rcpf(e + 1.0f);
}

__device__ __forceinline__ unsigned bf16r(float x) {   // RTNE f32->bf16 bits
    unsigned u = __float_as_uint(x);
    return (u + 0x7fffu + ((u >> 16) & 1u)) >> 16;
}
__device__ __forceinline__ unsigned cvt_pk(float lo, float hi) {  // 1 VALU op
    unsigned r;
    asm("v_cvt_pk_bf16_f32 %0, %1, %2" : "=v"(r) : "v"(lo), "v"(hi));
    return r;
}

// ---------------- fused encoder+hw: hw{p,n} = (x@We + be) @ W{p,n} ----------
// 64 rows per block (16 chunks of 4 rows); weights staged ONCE per block.

__global__ __launch_bounds__(256) void enc_hw_kernel(const float* __restrict__ x,
        const float* __restrict__ We, const float* __restrict__ be,
        const float* __restrict__ Wp, const float* __restrict__ Wn,
        float* __restrict__ hwp, float* __restrict__ hwn, int n) {
    __shared__ __align__(16) float Ws[128 * 64];   // 32KB
    __shared__ __align__(16) float Wps[64 * 64];   // 16KB
    __shared__ __align__(16) float Wns[64 * 64];   // 16KB
    __shared__ __align__(16) float xs[4 * 128];    // 2KB
    __shared__ __align__(16) float hs[4 * 64];     // 1KB
    int tid = threadIdx.x;
    for (int i = tid; i < 128 * 64; i += 256) Ws[i] = We[i];
    for (int i = tid; i < 64 * 64; i += 256) { Wps[i] = Wp[i]; Wns[i] = Wn[i]; }
    int r = tid >> 6, c = tid & 63;
    float bec = be[c];

    for (int chunk = 0; chunk < 16; ++chunk) {
        long row = (long)blockIdx.x * 64 + chunk * 4;
        __syncthreads();   // weights ready (iter 0) / prev chunk's reads done
        for (int i = tid; i < 4 * 128; i += 256) {
            long rr = row + (i >> 7);
            xs[i] = (rr < n) ? x[rr * 128 + (i & 127)] : 0.0f;
        }
        __syncthreads();
        float acc = bec;
        #pragma unroll 8
        for (int k = 0; k < 128; k += 4) {
            float4 xv = *(const float4*)&xs[r * 128 + k];
            acc += xv.x * Ws[(k+0)*64+c] + xv.y * Ws[(k+1)*64+c]
                 + xv.z * Ws[(k+2)*64+c] + xv.w * Ws[(k+3)*64+c];
        }
        hs[r * 64 + c] = acc;
        __syncthreads();
        float ap = 0.0f, an = 0.0f;
        #pragma unroll 4
        for (int k = 0; k < 64; k += 4) {
            float4 hv = *(const float4*)&hs[r * 64 + k];
            ap += hv.x*Wps[(k+0)*64+c] + hv.y*Wps[(k+1)*64+c] + hv.z*Wps[(k+2)*64+c] + hv.w*Wps[(k+3)*64+c];
            an += hv.x*Wns[(k+0)*64+c] + hv.y*Wns[(k+1)*64+c] + hv.z*Wns[(k+2)*64+c] + hv.w*Wns[(k+3)*64+c];
        }
        if (row + r < n) {
            hwp[(row + r) * 64 + c] = ap;
            hwn[(row + r) * 64 + c] = an;
        }
    }
}

// ---------------- CSR build: count / scan / fill ----------------

__global__ __launch_bounds__(256) void count_kernel(const int* __restrict__ pdst,
        const int* __restrict__ ndst, int* cntp, int* cntn, int nE) {
    int e = blockIdx.x * 256 + threadIdx.x;
    if (e < nE) {
        atomicAdd(&cntp[pdst[e]], 1);
        atomicAdd(&cntn[ndst[e]], 1);
    }
}

// grid = 2 blocks (0: pos, 1: neg), 1024 threads. Exclusive scan cnt->rowptr,
// dinv = rsqrt(cnt+1) (self-loop), cnt zeroed for reuse as fill cursor.
__global__ __launch_bounds__(1024) void scan_kernel(int* cntp, int* cntn,
        int* rpp, int* rpn, float* dinvp, float* dinvn, int n) {
    int* cnt  = blockIdx.x ? cntn  : cntp;
    int* rp   = blockIdx.x ? rpn   : rpp;
    float* dv = blockIdx.x ? dinvn : dinvp;
    __shared__ int ps[1024];
    int t = threadIdx.x;
    int CH = (n + 1023) / 1024;
    int beg = t * CH, end = beg + CH; if (end > n) end = n;
    int s = 0;
    for (int i = beg; i < end && i >= 0; ++i) s += cnt[i];
    ps[t] = s;
    __syncthreads();
    for (int off = 1; off < 1024; off <<= 1) {
        int v = (t >= off) ? ps[t - off] : 0;
        __syncthreads();
        ps[t] += v;
        __syncthreads();
    }
    int run = (t == 0) ? 0 : ps[t - 1];
    for (int i = beg; i < end && i >= 0; ++i) {
        int c = cnt[i];
        rp[i] = run; run += c;
        dv[i] = rsqrtf((float)c + 1.0f);
        cnt[i] = 0;
    }
    if (t == 1023) rp[n] = ps[1023];
}

// one launch, both graphs: blocks [0,nbE) pos, [nbE,2*nbE) neg
__global__ __launch_bounds__(256) void fill_both_kernel(
        const int* __restrict__ psrc, const int* __restrict__ pdst,
        const int* __restrict__ nsrc, const int* __restrict__ ndst,
        const int* __restrict__ rpp, const int* __restrict__ rpn,
        int* curp, int* curn, int* outp, int* outn, int nE, int nbE) {
    int b = blockIdx.x;
    if (b < nbE) {
        int e = b * 256 + threadIdx.x;
        if (e < nE) {
            int d = pdst[e];
            int pos = rpp[d] + atomicAdd(&curp[d], 1);
            outp[pos] = psrc[e];
        }
    } else {
        int e = (b - nbE) * 256 + threadIdx.x;
        if (e < nE) {
            int d = ndst[e];
            int pos = rpn[d] + atomicAdd(&curn[d], 1);
            outn[pos] = nsrc[e];
        }
    }
}

// ---------------- fused gather + dopri5 ODE, bf16 MFMA --------------------
// Block: 256 threads = 4 waves, ONE 16-node group. Wave w owns col-groups
// {2w, 2w+1} of the 128-wide state; w<2 -> pos-graph cols [0,64),
// w>=2 -> neg-graph cols [64,128). Prologue gathers y0 for this block's 16
// nodes directly from CSR+hw (in ws - NOT aliased with out) into per-thread
// y registers. Main loop identical to r15/r18/r20.

#define MFMA_(A, B, C) __builtin_amdgcn_mfma_f32_16x16x32_bf16(A, B, C, 0, 0, 0)

#define ODE_STAGE(BUF, YIM, CONSM) {                                                \
    char* yr_ = (BUF) + rowoff;                                                     \
    uint2v pk_;                                                                     \
    pk_.x = cvt_pk(YIM(0,0), YIM(0,1)); pk_.y = cvt_pk(YIM(0,2), YIM(0,3));         \
    *(uint2v*)(yr_ + (g0off ^ swz)) = pk_;                                          \
    pk_.x = cvt_pk(YIM(1,0), YIM(1,1)); pk_.y = cvt_pk(YIM(1,2), YIM(1,3));         \
    *(uint2v*)(yr_ + (g1off ^ swz)) = pk_;                                          \
    __syncthreads();                                                                \
    short8v b0 = *(const short8v*)(yr_ + ((  0 + q16) ^ swz));                      \
    short8v b1 = *(const short8v*)(yr_ + (( 64 + q16) ^ swz));                      \
    short8v b2 = *(const short8v*)(yr_ + ((128 + q16) ^ swz));                      \
    short8v b3 = *(const short8v*)(yr_ + ((192 + q16) ^ swz));                      \
    {                                                                               \
        f32x4 a = bias0;                                                            \
        a = MFMA_(af00, b0, a); a = MFMA_(af01, b1, a);                             \
        a = MFMA_(af02, b2, a); a = MFMA_(af03, b3, a);                             \
        CONSM(0, fast_tanh(a[0]), fast_tanh(a[1]), fast_tanh(a[2]), fast_tanh(a[3])); \
    }                                                                               \
    {                                                                               \
        f32x4 a = bias1;                                                            \
        a = MFMA_(af10, b0, a); a = MFMA_(af11, b1, a);                             \
        a = MFMA_(af12, b2, a); a = MFMA_(af13, b3, a);                             \
        CONSM(1, fast_tanh(a[0]), fast_tanh(a[1]), fast_tanh(a[2]), fast_tanh(a[3])); \
    } }

#define YI1(nn, r) (y[nn][r])
#define YI2(nn, r) (y[nn][r] + c21 * kp1[nn][r])
#define YI3(nn, r) (y[nn][r] + c31 * kp1[nn][r] + c32 * kp2[nn][r])
#define YI4(nn, r) (y[nn][r] + c41 * kp1[nn][r] + c42 * kp2[nn][r] + c43 * kp3[nn][r])
#define YI5(nn, r) (y[nn][r] + c51 * kp1[nn][r] + c52 * kp2[nn][r] + c53 * kp3[nn][r] \
                             + c54 * kp4[nn][r])
#define YI6(nn, r) (y[nn][r] + c61 * kp1[nn][r] + c62 * kp2[nn][r] + c63 * kp3[nn][r] \
                             + c64 * kp4[nn][r] + c65 * kp5[nn][r])

#define CONS1(nn,t0,t1,t2,t3) { kp1[nn][0]=t0; kp1[nn][1]=t1; kp1[nn][2]=t2; kp1[nn][3]=t3; }
#define CONS2(nn,t0,t1,t2,t3) { kp2[nn][0]=t0; kp2[nn][1]=t1; kp2[nn][2]=t2; kp2[nn][3]=t3; }
#define CONS3(nn,t0,t1,t2,t3) { kp3[nn][0]=t0; kp3[nn][1]=t1; kp3[nn][2]=t2; kp3[nn][3]=t3; }
#define CONS4(nn,t0,t1,t2,t3) { kp4[nn][0]=t0; kp4[nn][1]=t1; kp4[nn][2]=t2; kp4[nn][3]=t3; }
#define CONS5(nn,t0,t1,t2,t3) { kp5[nn][0]=t0; kp5[nn][1]=t1; kp5[nn][2]=t2; kp5[nn][3]=t3; }
#define CONS6(nn,t0,t1,t2,t3) {                                             \
    y[nn][0] += d1 * kp1[nn][0] + d3 * kp3[nn][0] + d4 * kp4[nn][0]         \
              + d5 * kp5[nn][0] + d6 * (t0);                                \
    y[nn][1] += d1 * kp1[nn][1] + d3 * kp3[nn][1] + d4 * kp4[nn][1]         \
              + d5 * kp5[nn][1] + d6 * (t1);                                \
    y[nn][2] += d1 * kp1[nn][2] + d3 * kp3[nn][2] + d4 * kp4[nn][2]         \
              + d5 * kp5[nn][2] + d6 * (t2);                                \
    y[nn][3] += d1 * kp1[nn][3] + d3 * kp3[nn][3] + d4 * kp4[nn][3]         \
              + d5 * kp5[nn][3] + d6 * (t3); }

__global__ __launch_bounds__(256) void ode_mfma_kernel(
        const float* __restrict__ hwp, const float* __restrict__ hwn,
        const int* __restrict__ srcp, const int* __restrict__ srcn,
        const int* __restrict__ rpp, const int* __restrict__ rpn,
        const float* __restrict__ dinvp, const float* __restrict__ dinvn,
        const float* __restrict__ gbp, const float* __restrict__ gbn,
        float* __restrict__ out, const float* __restrict__ W,
        const float* __restrict__ bb, const float* __restrict__ tt, int nrows) {
    __shared__ __align__(16) char smem[32768];
    int tid  = threadIdx.x;
    int lane = tid & 63, w = tid >> 6;       // w: col-group pair {2w, 2w+1}
    int l15 = lane & 15, q = lane >> 4;
    int swz = (lane & 7) << 4, q16 = q * 16, q8 = q * 8;
    int rowoff = l15 * 256;
    int g0off = w * 64 + q8, g1off = w * 64 + 32 + q8;

    // stage W^T (bf16, swizzled): Wt[c][d] = W[d][c]
    for (int i = tid; i < 16384; i += 256) {
        int d = i >> 7, c = i & 127;
        unsigned short hb = (unsigned short)bf16r(W[i]);
        *(unsigned short*)(smem + c * 256 + ((d * 2) ^ ((c & 7) << 4))) = hb;
    }
    __syncthreads();

    // cache my 8 A-fragments (2 col-groups x 4 k-slices) in registers
    const char* ab0 = smem + ((2 * w) * 16 + l15) * 256;
    const char* ab1 = smem + ((2 * w + 1) * 16 + l15) * 256;
    short8v af00 = *(const short8v*)(ab0 + ((  0 + q16) ^ swz));
    short8v af01 = *(const short8v*)(ab0 + (( 64 + q16) ^ swz));
    short8v af02 = *(const short8v*)(ab0 + ((128 + q16) ^ swz));
    short8v af03 = *(const short8v*)(ab0 + ((192 + q16) ^ swz));
    short8v af10 = *(const short8v*)(ab1 + ((  0 + q16) ^ swz));
    short8v af11 = *(const short8v*)(ab1 + (( 64 + q16) ^ swz));
    short8v af12 = *(const short8v*)(ab1 + ((128 + q16) ^ swz));
    short8v af13 = *(const short8v*)(ab1 + ((192 + q16) ^ swz));
    __syncthreads();   // all A-frags cached -> first 8KB may be clobbered

    float hstep = (tt[1] - tt[0]) * 0.03125f;
    float c21 = hstep * 0.2f;
    float c31 = hstep * 0.075f,               c32 = hstep * 0.225f;
    float c41 = hstep * 0.9777777777777777f,  c42 = hstep * -3.7333333333333334f,
          c43 = hstep * 3.5555555555555554f;
    float c51 = hstep * 2.9525986892242035f,  c52 = hstep * -11.595793324188385f,
          c53 = hstep * 9.822892851699436f,   c54 = hstep * -0.2908093278463649f;
    float c61 = hstep * 2.8462752525252526f,  c62 = hstep * -10.757575757575758f,
          c63 = hstep * 8.906422717743473f,   c64 = hstep * 0.2784090909090909f,
          c65 = hstep * -0.2735313036020583f;
    float d1 = hstep * 0.09114583333333333f,  d3 = hstep * 0.44923629829290207f,
          d4 = hstep * 0.6510416666666666f,   d5 = hstep * -0.322376179245283f,
          d6 = hstep * 0.13095238095238096f;

    // ODE bias (b_ode) for my 2 col-groups
    f32x4 bias0 = *(const f32x4*)&bb[(2 * w)     * 16 + q * 4];
    f32x4 bias1 = *(const f32x4*)&bb[(2 * w + 1) * 16 + q * 4];

    long grow = (long)blockIdx.x * 16 + l15;
    bool ok = grow < nrows;

    // ---- gather prologue: y0 for node `grow`, my 8 cols ----
    // w<2 -> pos graph (state cols 0-63); w>=2 -> neg graph (cols 64-127)
    const float* hwA  = (w < 2) ? hwp   : hwn;
    const int*   srcA = (w < 2) ? srcp  : srcn;
    const int*   rpA  = (w < 2) ? rpp   : rpn;
    const float* dvA  = (w < 2) ? dinvp : dinvn;
    const float* gbA  = (w < 2) ? gbp   : gbn;
    int col0 = ((2 * w) & 3) * 16 + q * 4;   // hw-row col of group 2w
    int col1 = col0 + 16;                    // hw-row col of group 2w+1

    f32x4 y[2];
    y[0] = (f32x4){0.0f, 0.0f, 0.0f, 0.0f};
    y[1] = (f32x4){0.0f, 0.0f, 0.0f, 0.0f};
    if (ok) {
        int dnode = (int)grow;
        int beg = rpA[dnode], end = rpA[dnode + 1];
        for (int i = beg; i < end; ++i) {
            int a = srcA[i];
            float dva = dvA[a];
            f32x4 h0 = *(const f32x4*)&hwA[(long)a * 64 + col0];
            f32x4 h1 = *(const f32x4*)&hwA[(long)a * 64 + col1];
            #pragma unroll
            for (int r = 0; r < 4; ++r) { y[0][r] += dva * h0[r]; y[1][r] += dva * h1[r]; }
        }
        float dvd = dvA[dnode];
        f32x4 h0 = *(const f32x4*)&hwA[(long)dnode * 64 + col0];
        f32x4 h1 = *(const f32x4*)&hwA[(long)dnode * 64 + col1];
        f32x4 gb0 = *(const f32x4*)&gbA[col0];
        f32x4 gb1 = *(const f32x4*)&gbA[col1];
        #pragma unroll
        for (int r = 0; r < 4; ++r) {
            y[0][r] = dvd * (y[0][r] + dvd * h0[r]) + gb0[r];
            y[1][r] = dvd * (y[1][r] + dvd * h1[r]) + gb1[r];
        }
    }

    char* bufA = smem;
    char* bufB = smem + 4096;

    f32x4 kp1[2], kp2[2], kp3[2], kp4[2], kp5[2];

    #pragma unroll 1
    for (int step = 0; step < 32; ++step) {
        ODE_STAGE(bufA, YI1, CONS1);
        ODE_STAGE(bufB, YI2, CONS2);
        ODE_STAGE(bufA, YI3, CONS3);
        ODE_STAGE(bufB, YI4, CONS4);
        ODE_STAGE(bufA, YI5, CONS5);
        ODE_STAGE(bufB, YI6, CONS6);
    }

    if (ok) {
        *(f32x4*)&out[grow * 128 + (2 * w)     * 16 + q * 4] = y[0];
        *(f32x4*)&out[grow * 128 + (2 * w + 1) * 16 + q * 4] = y[1];
    }
}

// ---------------------------------------------------------------------------

extern "C" void kernel_launch(void* const* d_in, const int* in_sizes, int n_in,
                              void* d_out, int out_size, void* d_ws, size_t ws_size,
                              hipStream_t stream) {
    const float* x     = (const float*)d_in[0];
    const int*   pei   = (const int*)d_in[1];
    const int*   nei   = (const int*)d_in[2];
    const float* t     = (const float*)d_in[3];
    const float* W_enc = (const float*)d_in[4];
    const float* b_enc = (const float*)d_in[5];
    const float* W_pos = (const float*)d_in[6];
    const float* b_pos = (const float*)d_in[7];
    const float* W_neg = (const float*)d_in[8];
    const float* b_neg = (const float*)d_in[9];
    const float* W_ode = (const float*)d_in[10];
    const float* b_ode = (const float*)d_in[11];

    int n  = in_sizes[0] / 128;   // 50000 nodes
    int nE = in_sizes[1] / 2;     // 800000 edges

    // ws layout (NO aliasing with d_out):
    //   floats hwp[n*64], hwn[n*64]  (25.6MB)
    //   ints   srcp[nE], srcn[nE], cntp[n], cntn[n], rpp[n+1], rpn[n+1] (7.2MB)
    //   floats dinvp[n], dinvn[n]    (0.4MB)           total ~33.2MB
    float* hwp = (float*)d_ws;
    float* hwn = hwp + (long)n * 64;
    int* srcp = (int*)(hwn + (long)n * 64);
    int* srcn = srcp + nE;
    int* cntp = srcn + nE;
    int* cntn = cntp + n;            // cntp,cntn contiguous -> single memset
    int* rpp  = cntn + n;
    int* rpn  = rpp + (n + 1);
    float* dinvp = (float*)(rpn + (n + 1));
    float* dinvn = dinvp + n;

    const int* psrc = pei;       const int* pdst = pei + nE;
    const int* nsrc = nei;       const int* ndst = nei + nE;

    int nbE = (nE + 255) / 256;

    hipMemsetAsync(cntp, 0, (size_t)(2 * n) * sizeof(int), stream);
    enc_hw_kernel   <<<(n + 63) / 64, 256, 0, stream>>>(x, W_enc, b_enc, W_pos, W_neg, hwp, hwn, n);
    count_kernel    <<<nbE, 256, 0, stream>>>(pdst, ndst, cntp, cntn, nE);
    scan_kernel     <<<2, 1024, 0, stream>>>(cntp, cntn, rpp, rpn, dinvp, dinvn, n);
    fill_both_kernel<<<2 * nbE, 256, 0, stream>>>(psrc, pdst, nsrc, ndst, rpp, rpn,
                                                  cntp, cntn, srcp, srcn, nE, nbE);
    ode_mfma_kernel <<<(n + 15) / 16, 256, 0, stream>>>(hwp, hwn, srcp, srcn, rpp, rpn,
                                                        dinvp, dinvn, b_pos, b_neg,
                                                        (float*)d_out, W_ode, b_ode, t, n);
}

// Round 23
// 1054.730 us; speedup vs baseline: 1.0008x; 1.0008x over previous
//
#include <hip/hip_runtime.h>
#include <hip/hip_bf16.h>

// ---------------------------------------------------------------------------
// DynamiSE: prep(count || enc+hw) -> scan -> fill -> fused (gather+dopri5) ODE.
// Round 23 = round-22 resubmit (r22 bench was an infra flake; container died
// before source push). r21 post-mortem: enc_hw weight re-reads were
// L2-resident (my 800MB "fix" priced L2 traffic at HBM rates; 64-row version
// was 12us WORSE).
//   - enc_hw reverted to r20's 4-row body.
//   - count fused into the same launch (prep_kernel): blocks [0,nbE) count
//     edges (no LDS, uniform early-return), blocks [nbE,+nbR) do the GEMM.
//     Independent work overlaps; one launch gap removed. Launches 6 -> 5.
//   ODE kernel byte-identical to r20/r21 (anchor: 755us, FETCH 194MB).
// ---------------------------------------------------------------------------

typedef __attribute__((ext_vector_type(8))) short short8v;   // 8 bf16 = 4 VGPR
typedef __attribute__((ext_vector_type(4))) float f32x4;
typedef __attribute__((ext_vector_type(2))) unsigned uint2v;

__device__ __forceinline__ float fast_tanh(float x) {
    float e = __builtin_amdgcn_exp2f(x * 2.8853900817779268f);
    return 1.0f - 2.0f * __builtin_amdgcn_rcpf(e + 1.0f);
}

__device__ __forceinline__ unsigned bf16r(float x) {   // RTNE f32->bf16 bits
    unsigned u = __float_as_uint(x);
    return (u + 0x7fffu + ((u >> 16) & 1u)) >> 16;
}
__device__ __forceinline__ unsigned cvt_pk(float lo, float hi) {  // 1 VALU op
    unsigned r;
    asm("v_cvt_pk_bf16_f32 %0, %1, %2" : "=v"(r) : "v"(lo), "v"(hi));
    return r;
}

// ---------------- prep: blocks [0,nbE) count edges; rest do enc+hw GEMM ----

__global__ __launch_bounds__(256) void prep_kernel(const float* __restrict__ x,
        const float* __restrict__ We, const float* __restrict__ be,
        const float* __restrict__ Wp, const float* __restrict__ Wn,
        float* __restrict__ hwp, float* __restrict__ hwn,
        const int* __restrict__ pdst, const int* __restrict__ ndst,
        int* cntp, int* cntn, int n, int nE, int nbE) {
    __shared__ __align__(16) float Ws[128 * 64];   // 32KB
    __shared__ __align__(16) float Wps[64 * 64];   // 16KB
    __shared__ __align__(16) float Wns[64 * 64];   // 16KB
    __shared__ __align__(16) float xs[4 * 128];    // 2KB
    __shared__ __align__(16) float hs[4 * 64];     // 1KB
    int tid = threadIdx.x;

    if ((int)blockIdx.x < nbE) {   // -------- count branch (no LDS, no barrier)
        int e = blockIdx.x * 256 + tid;
        if (e < nE) {
            atomicAdd(&cntp[pdst[e]], 1);
            atomicAdd(&cntn[ndst[e]], 1);
        }
        return;
    }
    // -------- enc+hw branch (r20 4-row body) --------
    int gb = blockIdx.x - nbE;
    for (int i = tid; i < 128 * 64; i += 256) Ws[i] = We[i];
    for (int i = tid; i < 64 * 64; i += 256) { Wps[i] = Wp[i]; Wns[i] = Wn[i]; }
    long row = (long)gb * 4;
    for (int i = tid; i < 4 * 128; i += 256) {
        long rr = row + (i >> 7);
        xs[i] = (rr < n) ? x[rr * 128 + (i & 127)] : 0.0f;
    }
    __syncthreads();
    int r = tid >> 6, c = tid & 63;
    float acc = be[c];
    #pragma unroll 8
    for (int k = 0; k < 128; k += 4) {
        float4 xv = *(const float4*)&xs[r * 128 + k];
        acc += xv.x * Ws[(k+0)*64+c] + xv.y * Ws[(k+1)*64+c]
             + xv.z * Ws[(k+2)*64+c] + xv.w * Ws[(k+3)*64+c];
    }
    hs[r * 64 + c] = acc;
    __syncthreads();
    float ap = 0.0f, an = 0.0f;
    #pragma unroll 4
    for (int k = 0; k < 64; k += 4) {
        float4 hv = *(const float4*)&hs[r * 64 + k];
        ap += hv.x*Wps[(k+0)*64+c] + hv.y*Wps[(k+1)*64+c] + hv.z*Wps[(k+2)*64+c] + hv.w*Wps[(k+3)*64+c];
        an += hv.x*Wns[(k+0)*64+c] + hv.y*Wns[(k+1)*64+c] + hv.z*Wns[(k+2)*64+c] + hv.w*Wns[(k+3)*64+c];
    }
    if (row + r < n) {
        hwp[(row + r) * 64 + c] = ap;
        hwn[(row + r) * 64 + c] = an;
    }
}

// ---------------- CSR build: scan / fill ----------------

// grid = 2 blocks (0: pos, 1: neg), 1024 threads. Exclusive scan cnt->rowptr,
// dinv = rsqrt(cnt+1) (self-loop), cnt zeroed for reuse as fill cursor.
__global__ __launch_bounds__(1024) void scan_kernel(int* cntp, int* cntn,
        int* rpp, int* rpn, float* dinvp, float* dinvn, int n) {
    int* cnt  = blockIdx.x ? cntn  : cntp;
    int* rp   = blockIdx.x ? rpn   : rpp;
    float* dv = blockIdx.x ? dinvn : dinvp;
    __shared__ int ps[1024];
    int t = threadIdx.x;
    int CH = (n + 1023) / 1024;
    int beg = t * CH, end = beg + CH; if (end > n) end = n;
    int s = 0;
    for (int i = beg; i < end && i >= 0; ++i) s += cnt[i];
    ps[t] = s;
    __syncthreads();
    for (int off = 1; off < 1024; off <<= 1) {
        int v = (t >= off) ? ps[t - off] : 0;
        __syncthreads();
        ps[t] += v;
        __syncthreads();
    }
    int run = (t == 0) ? 0 : ps[t - 1];
    for (int i = beg; i < end && i >= 0; ++i) {
        int c = cnt[i];
        rp[i] = run; run += c;
        dv[i] = rsqrtf((float)c + 1.0f);
        cnt[i] = 0;
    }
    if (t == 1023) rp[n] = ps[1023];
}

// one launch, both graphs: blocks [0,nbE) pos, [nbE,2*nbE) neg
__global__ __launch_bounds__(256) void fill_both_kernel(
        const int* __restrict__ psrc, const int* __restrict__ pdst,
        const int* __restrict__ nsrc, const int* __restrict__ ndst,
        const int* __restrict__ rpp, const int* __restrict__ rpn,
        int* curp, int* curn, int* outp, int* outn, int nE, int nbE) {
    int b = blockIdx.x;
    if (b < nbE) {
        int e = b * 256 + threadIdx.x;
        if (e < nE) {
            int d = pdst[e];
            int pos = rpp[d] + atomicAdd(&curp[d], 1);
            outp[pos] = psrc[e];
        }
    } else {
        int e = (b - nbE) * 256 + threadIdx.x;
        if (e < nE) {
            int d = ndst[e];
            int pos = rpn[d] + atomicAdd(&curn[d], 1);
            outn[pos] = nsrc[e];
        }
    }
}

// ---------------- fused gather + dopri5 ODE, bf16 MFMA --------------------
// Block: 256 threads = 4 waves, ONE 16-node group. Wave w owns col-groups
// {2w, 2w+1} of the 128-wide state; w<2 -> pos-graph cols [0,64),
// w>=2 -> neg-graph cols [64,128). Prologue gathers y0 for this block's 16
// nodes directly from CSR+hw (in ws - NOT aliased with out) into per-thread
// y registers. Main loop identical to r15/r18/r20/r21.

#define MFMA_(A, B, C) __builtin_amdgcn_mfma_f32_16x16x32_bf16(A, B, C, 0, 0, 0)

#define ODE_STAGE(BUF, YIM, CONSM) {                                                \
    char* yr_ = (BUF) + rowoff;                                                     \
    uint2v pk_;                                                                     \
    pk_.x = cvt_pk(YIM(0,0), YIM(0,1)); pk_.y = cvt_pk(YIM(0,2), YIM(0,3));         \
    *(uint2v*)(yr_ + (g0off ^ swz)) = pk_;                                          \
    pk_.x = cvt_pk(YIM(1,0), YIM(1,1)); pk_.y = cvt_pk(YIM(1,2), YIM(1,3));         \
    *(uint2v*)(yr_ + (g1off ^ swz)) = pk_;                                          \
    __syncthreads();                                                                \
    short8v b0 = *(const short8v*)(yr_ + ((  0 + q16) ^ swz));                      \
    short8v b1 = *(const short8v*)(yr_ + (( 64 + q16) ^ swz));                      \
    short8v b2 = *(const short8v*)(yr_ + ((128 + q16) ^ swz));                      \
    short8v b3 = *(const short8v*)(yr_ + ((192 + q16) ^ swz));                      \
    {                                                                               \
        f32x4 a = bias0;                                                            \
        a = MFMA_(af00, b0, a); a = MFMA_(af01, b1, a);                             \
        a = MFMA_(af02, b2, a); a = MFMA_(af03, b3, a);                             \
        CONSM(0, fast_tanh(a[0]), fast_tanh(a[1]), fast_tanh(a[2]), fast_tanh(a[3])); \
    }                                                                               \
    {                                                                               \
        f32x4 a = bias1;                                                            \
        a = MFMA_(af10, b0, a); a = MFMA_(af11, b1, a);                             \
        a = MFMA_(af12, b2, a); a = MFMA_(af13, b3, a);                             \
        CONSM(1, fast_tanh(a[0]), fast_tanh(a[1]), fast_tanh(a[2]), fast_tanh(a[3])); \
    } }

#define YI1(nn, r) (y[nn][r])
#define YI2(nn, r) (y[nn][r] + c21 * kp1[nn][r])
#define YI3(nn, r) (y[nn][r] + c31 * kp1[nn][r] + c32 * kp2[nn][r])
#define YI4(nn, r) (y[nn][r] + c41 * kp1[nn][r] + c42 * kp2[nn][r] + c43 * kp3[nn][r])
#define YI5(nn, r) (y[nn][r] + c51 * kp1[nn][r] + c52 * kp2[nn][r] + c53 * kp3[nn][r] \
                             + c54 * kp4[nn][r])
#define YI6(nn, r) (y[nn][r] + c61 * kp1[nn][r] + c62 * kp2[nn][r] + c63 * kp3[nn][r] \
                             + c64 * kp4[nn][r] + c65 * kp5[nn][r])

#define CONS1(nn,t0,t1,t2,t3) { kp1[nn][0]=t0; kp1[nn][1]=t1; kp1[nn][2]=t2; kp1[nn][3]=t3; }
#define CONS2(nn,t0,t1,t2,t3) { kp2[nn][0]=t0; kp2[nn][1]=t1; kp2[nn][2]=t2; kp2[nn][3]=t3; }
#define CONS3(nn,t0,t1,t2,t3) { kp3[nn][0]=t0; kp3[nn][1]=t1; kp3[nn][2]=t2; kp3[nn][3]=t3; }
#define CONS4(nn,t0,t1,t2,t3) { kp4[nn][0]=t0; kp4[nn][1]=t1; kp4[nn][2]=t2; kp4[nn][3]=t3; }
#define CONS5(nn,t0,t1,t2,t3) { kp5[nn][0]=t0; kp5[nn][1]=t1; kp5[nn][2]=t2; kp5[nn][3]=t3; }
#define CONS6(nn,t0,t1,t2,t3) {                                             \
    y[nn][0] += d1 * kp1[nn][0] + d3 * kp3[nn][0] + d4 * kp4[nn][0]         \
              + d5 * kp5[nn][0] + d6 * (t0);                                \
    y[nn][1] += d1 * kp1[nn][1] + d3 * kp3[nn][1] + d4 * kp4[nn][1]         \
              + d5 * kp5[nn][1] + d6 * (t1);                                \
    y[nn][2] += d1 * kp1[nn][2] + d3 * kp3[nn][2] + d4 * kp4[nn][2]         \
              + d5 * kp5[nn][2] + d6 * (t2);                                \
    y[nn][3] += d1 * kp1[nn][3] + d3 * kp3[nn][3] + d4 * kp4[nn][3]         \
              + d5 * kp5[nn][3] + d6 * (t3); }

__global__ __launch_bounds__(256) void ode_mfma_kernel(
        const float* __restrict__ hwp, const float* __restrict__ hwn,
        const int* __restrict__ srcp, const int* __restrict__ srcn,
        const int* __restrict__ rpp, const int* __restrict__ rpn,
        const float* __restrict__ dinvp, const float* __restrict__ dinvn,
        const float* __restrict__ gbp, const float* __restrict__ gbn,
        float* __restrict__ out, const float* __restrict__ W,
        const float* __restrict__ bb, const float* __restrict__ tt, int nrows) {
    __shared__ __align__(16) char smem[32768];
    int tid  = threadIdx.x;
    int lane = tid & 63, w = tid >> 6;       // w: col-group pair {2w, 2w+1}
    int l15 = lane & 15, q = lane >> 4;
    int swz = (lane & 7) << 4, q16 = q * 16, q8 = q * 8;
    int rowoff = l15 * 256;
    int g0off = w * 64 + q8, g1off = w * 64 + 32 + q8;

    // stage W^T (bf16, swizzled): Wt[c][d] = W[d][c]
    for (int i = tid; i < 16384; i += 256) {
        int d = i >> 7, c = i & 127;
        unsigned short hb = (unsigned short)bf16r(W[i]);
        *(unsigned short*)(smem + c * 256 + ((d * 2) ^ ((c & 7) << 4))) = hb;
    }
    __syncthreads();

    // cache my 8 A-fragments (2 col-groups x 4 k-slices) in registers
    const char* ab0 = smem + ((2 * w) * 16 + l15) * 256;
    const char* ab1 = smem + ((2 * w + 1) * 16 + l15) * 256;
    short8v af00 = *(const short8v*)(ab0 + ((  0 + q16) ^ swz));
    short8v af01 = *(const short8v*)(ab0 + (( 64 + q16) ^ swz));
    short8v af02 = *(const short8v*)(ab0 + ((128 + q16) ^ swz));
    short8v af03 = *(const short8v*)(ab0 + ((192 + q16) ^ swz));
    short8v af10 = *(const short8v*)(ab1 + ((  0 + q16) ^ swz));
    short8v af11 = *(const short8v*)(ab1 + (( 64 + q16) ^ swz));
    short8v af12 = *(const short8v*)(ab1 + ((128 + q16) ^ swz));
    short8v af13 = *(const short8v*)(ab1 + ((192 + q16) ^ swz));
    __syncthreads();   // all A-frags cached -> first 8KB may be clobbered

    float hstep = (tt[1] - tt[0]) * 0.03125f;
    float c21 = hstep * 0.2f;
    float c31 = hstep * 0.075f,               c32 = hstep * 0.225f;
    float c41 = hstep * 0.9777777777777777f,  c42 = hstep * -3.7333333333333334f,
          c43 = hstep * 3.5555555555555554f;
    float c51 = hstep * 2.9525986892242035f,  c52 = hstep * -11.595793324188385f,
          c53 = hstep * 9.822892851699436f,   c54 = hstep * -0.2908093278463649f;
    float c61 = hstep * 2.8462752525252526f,  c62 = hstep * -10.757575757575758f,
          c63 = hstep * 8.906422717743473f,   c64 = hstep * 0.2784090909090909f,
          c65 = hstep * -0.2735313036020583f;
    float d1 = hstep * 0.09114583333333333f,  d3 = hstep * 0.44923629829290207f,
          d4 = hstep * 0.6510416666666666f,   d5 = hstep * -0.322376179245283f,
          d6 = hstep * 0.13095238095238096f;

    // ODE bias (b_ode) for my 2 col-groups
    f32x4 bias0 = *(const f32x4*)&bb[(2 * w)     * 16 + q * 4];
    f32x4 bias1 = *(const f32x4*)&bb[(2 * w + 1) * 16 + q * 4];

    long grow = (long)blockIdx.x * 16 + l15;
    bool ok = grow < nrows;

    // ---- gather prologue: y0 for node `grow`, my 8 cols ----
    // w<2 -> pos graph (state cols 0-63); w>=2 -> neg graph (cols 64-127)
    const float* hwA  = (w < 2) ? hwp   : hwn;
    const int*   srcA = (w < 2) ? srcp  : srcn;
    const int*   rpA  = (w < 2) ? rpp   : rpn;
    const float* dvA  = (w < 2) ? dinvp : dinvn;
    const float* gbA  = (w < 2) ? gbp   : gbn;
    int col0 = ((2 * w) & 3) * 16 + q * 4;   // hw-row col of group 2w
    int col1 = col0 + 16;                    // hw-row col of group 2w+1

    f32x4 y[2];
    y[0] = (f32x4){0.0f, 0.0f, 0.0f, 0.0f};
    y[1] = (f32x4){0.0f, 0.0f, 0.0f, 0.0f};
    if (ok) {
        int dnode = (int)grow;
        int beg = rpA[dnode], end = rpA[dnode + 1];
        for (int i = beg; i < end; ++i) {
            int a = srcA[i];
            float dva = dvA[a];
            f32x4 h0 = *(const f32x4*)&hwA[(long)a * 64 + col0];
            f32x4 h1 = *(const f32x4*)&hwA[(long)a * 64 + col1];
            #pragma unroll
            for (int r = 0; r < 4; ++r) { y[0][r] += dva * h0[r]; y[1][r] += dva * h1[r]; }
        }
        float dvd = dvA[dnode];
        f32x4 h0 = *(const f32x4*)&hwA[(long)dnode * 64 + col0];
        f32x4 h1 = *(const f32x4*)&hwA[(long)dnode * 64 + col1];
        f32x4 gb0 = *(const f32x4*)&gbA[col0];
        f32x4 gb1 = *(const f32x4*)&gbA[col1];
        #pragma unroll
        for (int r = 0; r < 4; ++r) {
            y[0][r] = dvd * (y[0][r] + dvd * h0[r]) + gb0[r];
            y[1][r] = dvd * (y[1][r] + dvd * h1[r]) + gb1[r];
        }
    }

    char* bufA = smem;
    char* bufB = smem + 4096;

    f32x4 kp1[2], kp2[2], kp3[2], kp4[2], kp5[2];

    #pragma unroll 1
    for (int step = 0; step < 32; ++step) {
        ODE_STAGE(bufA, YI1, CONS1);
        ODE_STAGE(bufB, YI2, CONS2);
        ODE_STAGE(bufA, YI3, CONS3);
        ODE_STAGE(bufB, YI4, CONS4);
        ODE_STAGE(bufA, YI5, CONS5);
        ODE_STAGE(bufB, YI6, CONS6);
    }

    if (ok) {
        *(f32x4*)&out[grow * 128 + (2 * w)     * 16 + q * 4] = y[0];
        *(f32x4*)&out[grow * 128 + (2 * w + 1) * 16 + q * 4] = y[1];
    }
}

// ---------------------------------------------------------------------------

extern "C" void kernel_launch(void* const* d_in, const int* in_sizes, int n_in,
                              void* d_out, int out_size, void* d_ws, size_t ws_size,
                              hipStream_t stream) {
    const float* x     = (const float*)d_in[0];
    const int*   pei   = (const int*)d_in[1];
    const int*   nei   = (const int*)d_in[2];
    const float* t     = (const float*)d_in[3];
    const float* W_enc = (const float*)d_in[4];
    const float* b_enc = (const float*)d_in[5];
    const float* W_pos = (const float*)d_in[6];
    const float* b_pos = (const float*)d_in[7];
    const float* W_neg = (const float*)d_in[8];
    const float* b_neg = (const float*)d_in[9];
    const float* W_ode = (const float*)d_in[10];
    const float* b_ode = (const float*)d_in[11];

    int n  = in_sizes[0] / 128;   // 50000 nodes
    int nE = in_sizes[1] / 2;     // 800000 edges

    // ws layout (NO aliasing with d_out):
    //   floats hwp[n*64], hwn[n*64]  (25.6MB)
    //   ints   srcp[nE], srcn[nE], cntp[n], cntn[n], rpp[n+1], rpn[n+1] (7.2MB)
    //   floats dinvp[n], dinvn[n]    (0.4MB)           total ~33.2MB
    float* hwp = (float*)d_ws;
    float* hwn = hwp + (long)n * 64;
    int* srcp = (int*)(hwn + (long)n * 64);
    int* srcn = srcp + nE;
    int* cntp = srcn + nE;
    int* cntn = cntp + n;            // cntp,cntn contiguous -> single memset
    int* rpp  = cntn + n;
    int* rpn  = rpp + (n + 1);
    float* dinvp = (float*)(rpn + (n + 1));
    float* dinvn = dinvp + n;

    const int* psrc = pei;       const int* pdst = pei + nE;
    const int* nsrc = nei;       const int* ndst = nei + nE;

    int nbE = (nE + 255) / 256;
    int nbR = (n + 3) / 4;

    hipMemsetAsync(cntp, 0, (size_t)(2 * n) * sizeof(int), stream);
    prep_kernel     <<<nbE + nbR, 256, 0, stream>>>(x, W_enc, b_enc, W_pos, W_neg,
                                                    hwp, hwn, pdst, ndst, cntp, cntn,
                                                    n, nE, nbE);
    scan_kernel     <<<2, 1024, 0, stream>>>(cntp, cntn, rpp, rpn, dinvp, dinvn, n);
    fill_both_kernel<<<2 * nbE, 256, 0, stream>>>(psrc, pdst, nsrc, ndst, rpp, rpn,
                                                  cntp, cntn, srcp, srcn, nE, nbE);
    ode_mfma_kernel <<<(n + 15) / 16, 256, 0, stream>>>(hwp, hwn, srcp, srcn, rpp, rpn,
                                                        dinvp, dinvn, b_pos, b_neg,
                                                        (float*)d_out, W_ode, b_ode, t, n);
}

// Round 24
// 1033.604 us; speedup vs baseline: 1.0213x; 1.0204x over previous
//
#include <hip/hip_runtime.h>
#include <hip/hip_bf16.h>

// ---------------------------------------------------------------------------
// DynamiSE: prep(count || enc+hw) -> scan -> fill -> fused (gather+dopri5) ODE.
// Round 24: unbind the ODE's occupancy from LDS.
//   r23: ODE 759us @ occupancy 30% -- LDS 32KB (5 blocks/CU) binds, but 32KB
//   of it exists only to stage Wt for the ONE-TIME A-frag load. This round:
//   A-frags load directly from global W (8 stride-128 f32 reads per frag,
//   L2-hot; XOR algebra verified: frag j of group g = W[32j+8q+e][g*16+l15],
//   cvt_pk RTNE == old bf16r staging, numerics identical). LDS -> 8KB
//   (yi dbuf only) -> VGPR binds at 6 blocks/CU = 24 waves/CU (+20%).
//   Front-end unchanged from r23.
// ---------------------------------------------------------------------------

typedef __attribute__((ext_vector_type(8))) short short8v;   // 8 bf16 = 4 VGPR
typedef __attribute__((ext_vector_type(4))) float f32x4;
typedef __attribute__((ext_vector_type(2))) unsigned uint2v;

__device__ __forceinline__ float fast_tanh(float x) {
    float e = __builtin_amdgcn_exp2f(x * 2.8853900817779268f);
    return 1.0f - 2.0f * __builtin_amdgcn_rcpf(e + 1.0f);
}

__device__ __forceinline__ unsigned cvt_pk(float lo, float hi) {  // 1 VALU op
    unsigned r;
    asm("v_cvt_pk_bf16_f32 %0, %1, %2" : "=v"(r) : "v"(lo), "v"(hi));
    return r;
}

// A-frag j for W^T column `col`: 8 consecutive W rows starting at row0, bf16.
__device__ __forceinline__ short8v packAfrag(const float* __restrict__ p) {
    union { short8v s; unsigned u[4]; } t;
    t.u[0] = cvt_pk(p[0 * 128], p[1 * 128]);
    t.u[1] = cvt_pk(p[2 * 128], p[3 * 128]);
    t.u[2] = cvt_pk(p[4 * 128], p[5 * 128]);
    t.u[3] = cvt_pk(p[6 * 128], p[7 * 128]);
    return t.s;
}

// ---------------- prep: blocks [0,nbE) count edges; rest do enc+hw GEMM ----

__global__ __launch_bounds__(256) void prep_kernel(const float* __restrict__ x,
        const float* __restrict__ We, const float* __restrict__ be,
        const float* __restrict__ Wp, const float* __restrict__ Wn,
        float* __restrict__ hwp, float* __restrict__ hwn,
        const int* __restrict__ pdst, const int* __restrict__ ndst,
        int* cntp, int* cntn, int n, int nE, int nbE) {
    __shared__ __align__(16) float Ws[128 * 64];   // 32KB
    __shared__ __align__(16) float Wps[64 * 64];   // 16KB
    __shared__ __align__(16) float Wns[64 * 64];   // 16KB
    __shared__ __align__(16) float xs[4 * 128];    // 2KB
    __shared__ __align__(16) float hs[4 * 64];     // 1KB
    int tid = threadIdx.x;

    if ((int)blockIdx.x < nbE) {   // -------- count branch (no LDS, no barrier)
        int e = blockIdx.x * 256 + tid;
        if (e < nE) {
            atomicAdd(&cntp[pdst[e]], 1);
            atomicAdd(&cntn[ndst[e]], 1);
        }
        return;
    }
    // -------- enc+hw branch (r20 4-row body) --------
    int gb = blockIdx.x - nbE;
    for (int i = tid; i < 128 * 64; i += 256) Ws[i] = We[i];
    for (int i = tid; i < 64 * 64; i += 256) { Wps[i] = Wp[i]; Wns[i] = Wn[i]; }
    long row = (long)gb * 4;
    for (int i = tid; i < 4 * 128; i += 256) {
        long rr = row + (i >> 7);
        xs[i] = (rr < n) ? x[rr * 128 + (i & 127)] : 0.0f;
    }
    __syncthreads();
    int r = tid >> 6, c = tid & 63;
    float acc = be[c];
    #pragma unroll 8
    for (int k = 0; k < 128; k += 4) {
        float4 xv = *(const float4*)&xs[r * 128 + k];
        acc += xv.x * Ws[(k+0)*64+c] + xv.y * Ws[(k+1)*64+c]
             + xv.z * Ws[(k+2)*64+c] + xv.w * Ws[(k+3)*64+c];
    }
    hs[r * 64 + c] = acc;
    __syncthreads();
    float ap = 0.0f, an = 0.0f;
    #pragma unroll 4
    for (int k = 0; k < 64; k += 4) {
        float4 hv = *(const float4*)&hs[r * 64 + k];
        ap += hv.x*Wps[(k+0)*64+c] + hv.y*Wps[(k+1)*64+c] + hv.z*Wps[(k+2)*64+c] + hv.w*Wps[(k+3)*64+c];
        an += hv.x*Wns[(k+0)*64+c] + hv.y*Wns[(k+1)*64+c] + hv.z*Wns[(k+2)*64+c] + hv.w*Wns[(k+3)*64+c];
    }
    if (row + r < n) {
        hwp[(row + r) * 64 + c] = ap;
        hwn[(row + r) * 64 + c] = an;
    }
}

// ---------------- CSR build: scan / fill ----------------

__global__ __launch_bounds__(1024) void scan_kernel(int* cntp, int* cntn,
        int* rpp, int* rpn, float* dinvp, float* dinvn, int n) {
    int* cnt  = blockIdx.x ? cntn  : cntp;
    int* rp   = blockIdx.x ? rpn   : rpp;
    float* dv = blockIdx.x ? dinvn : dinvp;
    __shared__ int ps[1024];
    int t = threadIdx.x;
    int CH = (n + 1023) / 1024;
    int beg = t * CH, end = beg + CH; if (end > n) end = n;
    int s = 0;
    for (int i = beg; i < end && i >= 0; ++i) s += cnt[i];
    ps[t] = s;
    __syncthreads();
    for (int off = 1; off < 1024; off <<= 1) {
        int v = (t >= off) ? ps[t - off] : 0;
        __syncthreads();
        ps[t] += v;
        __syncthreads();
    }
    int run = (t == 0) ? 0 : ps[t - 1];
    for (int i = beg; i < end && i >= 0; ++i) {
        int c = cnt[i];
        rp[i] = run; run += c;
        dv[i] = rsqrtf((float)c + 1.0f);
        cnt[i] = 0;
    }
    if (t == 1023) rp[n] = ps[1023];
}

// one launch, both graphs: blocks [0,nbE) pos, [nbE,2*nbE) neg
__global__ __launch_bounds__(256) void fill_both_kernel(
        const int* __restrict__ psrc, const int* __restrict__ pdst,
        const int* __restrict__ nsrc, const int* __restrict__ ndst,
        const int* __restrict__ rpp, const int* __restrict__ rpn,
        int* curp, int* curn, int* outp, int* outn, int nE, int nbE) {
    int b = blockIdx.x;
    if (b < nbE) {
        int e = b * 256 + threadIdx.x;
        if (e < nE) {
            int d = pdst[e];
            int pos = rpp[d] + atomicAdd(&curp[d], 1);
            outp[pos] = psrc[e];
        }
    } else {
        int e = (b - nbE) * 256 + threadIdx.x;
        if (e < nE) {
            int d = ndst[e];
            int pos = rpn[d] + atomicAdd(&curn[d], 1);
            outn[pos] = nsrc[e];
        }
    }
}

// ---------------- fused gather + dopri5 ODE, bf16 MFMA --------------------
// Block: 256 threads = 4 waves, ONE 16-node group. Wave w owns col-groups
// {2w, 2w+1}; w<2 -> pos graph cols [0,64), w>=2 -> neg cols [64,128).
// A-frags loaded DIRECT from global W (L2-hot); LDS = 8KB yi dbuf only.

#define MFMA_(A, B, C) __builtin_amdgcn_mfma_f32_16x16x32_bf16(A, B, C, 0, 0, 0)

#define ODE_STAGE(BUF, YIM, CONSM) {                                                \
    char* yr_ = (BUF) + rowoff;                                                     \
    uint2v pk_;                                                                     \
    pk_.x = cvt_pk(YIM(0,0), YIM(0,1)); pk_.y = cvt_pk(YIM(0,2), YIM(0,3));         \
    *(uint2v*)(yr_ + (g0off ^ swz)) = pk_;                                          \
    pk_.x = cvt_pk(YIM(1,0), YIM(1,1)); pk_.y = cvt_pk(YIM(1,2), YIM(1,3));         \
    *(uint2v*)(yr_ + (g1off ^ swz)) = pk_;                                          \
    __syncthreads();                                                                \
    short8v b0 = *(const short8v*)(yr_ + ((  0 + q16) ^ swz));                      \
    short8v b1 = *(const short8v*)(yr_ + (( 64 + q16) ^ swz));                      \
    short8v b2 = *(const short8v*)(yr_ + ((128 + q16) ^ swz));                      \
    short8v b3 = *(const short8v*)(yr_ + ((192 + q16) ^ swz));                      \
    {                                                                               \
        f32x4 a = bias0;                                                            \
        a = MFMA_(af00, b0, a); a = MFMA_(af01, b1, a);                             \
        a = MFMA_(af02, b2, a); a = MFMA_(af03, b3, a);                             \
        CONSM(0, fast_tanh(a[0]), fast_tanh(a[1]), fast_tanh(a[2]), fast_tanh(a[3])); \
    }                                                                               \
    {                                                                               \
        f32x4 a = bias1;                                                            \
        a = MFMA_(af10, b0, a); a = MFMA_(af11, b1, a);                             \
        a = MFMA_(af12, b2, a); a = MFMA_(af13, b3, a);                             \
        CONSM(1, fast_tanh(a[0]), fast_tanh(a[1]), fast_tanh(a[2]), fast_tanh(a[3])); \
    } }

#define YI1(nn, r) (y[nn][r])
#define YI2(nn, r) (y[nn][r] + c21 * kp1[nn][r])
#define YI3(nn, r) (y[nn][r] + c31 * kp1[nn][r] + c32 * kp2[nn][r])
#define YI4(nn, r) (y[nn][r] + c41 * kp1[nn][r] + c42 * kp2[nn][r] + c43 * kp3[nn][r])
#define YI5(nn, r) (y[nn][r] + c51 * kp1[nn][r] + c52 * kp2[nn][r] + c53 * kp3[nn][r] \
                             + c54 * kp4[nn][r])
#define YI6(nn, r) (y[nn][r] + c61 * kp1[nn][r] + c62 * kp2[nn][r] + c63 * kp3[nn][r] \
                             + c64 * kp4[nn][r] + c65 * kp5[nn][r])

#define CONS1(nn,t0,t1,t2,t3) { kp1[nn][0]=t0; kp1[nn][1]=t1; kp1[nn][2]=t2; kp1[nn][3]=t3; }
#define CONS2(nn,t0,t1,t2,t3) { kp2[nn][0]=t0; kp2[nn][1]=t1; kp2[nn][2]=t2; kp2[nn][3]=t3; }
#define CONS3(nn,t0,t1,t2,t3) { kp3[nn][0]=t0; kp3[nn][1]=t1; kp3[nn][2]=t2; kp3[nn][3]=t3; }
#define CONS4(nn,t0,t1,t2,t3) { kp4[nn][0]=t0; kp4[nn][1]=t1; kp4[nn][2]=t2; kp4[nn][3]=t3; }
#define CONS5(nn,t0,t1,t2,t3) { kp5[nn][0]=t0; kp5[nn][1]=t1; kp5[nn][2]=t2; kp5[nn][3]=t3; }
#define CONS6(nn,t0,t1,t2,t3) {                                             \
    y[nn][0] += d1 * kp1[nn][0] + d3 * kp3[nn][0] + d4 * kp4[nn][0]         \
              + d5 * kp5[nn][0] + d6 * (t0);                                \
    y[nn][1] += d1 * kp1[nn][1] + d3 * kp3[nn][1] + d4 * kp4[nn][1]         \
              + d5 * kp5[nn][1] + d6 * (t1);                                \
    y[nn][2] += d1 * kp1[nn][2] + d3 * kp3[nn][2] + d4 * kp4[nn][2]         \
              + d5 * kp5[nn][2] + d6 * (t2);                                \
    y[nn][3] += d1 * kp1[nn][3] + d3 * kp3[nn][3] + d4 * kp4[nn][3]         \
              + d5 * kp5[nn][3] + d6 * (t3); }

__global__ __launch_bounds__(256) void ode_mfma_kernel(
        const float* __restrict__ hwp, const float* __restrict__ hwn,
        const int* __restrict__ srcp, const int* __restrict__ srcn,
        const int* __restrict__ rpp, const int* __restrict__ rpn,
        const float* __restrict__ dinvp, const float* __restrict__ dinvn,
        const float* __restrict__ gbp, const float* __restrict__ gbn,
        float* __restrict__ out, const float* __restrict__ W,
        const float* __restrict__ bb, const float* __restrict__ tt, int nrows) {
    __shared__ __align__(16) char smem[8192];   // yi double-buffer ONLY
    int tid  = threadIdx.x;
    int lane = tid & 63, w = tid >> 6;       // w: col-group pair {2w, 2w+1}
    int l15 = lane & 15, q = lane >> 4;
    int swz = (lane & 7) << 4, q16 = q * 16, q8 = q * 8;
    int rowoff = l15 * 256;
    int g0off = w * 64 + q8, g1off = w * 64 + 32 + q8;

    // A-frags direct from global W (f32 [128][128]); frag j of col-group g:
    // W[32j+8q+e][g*16+l15], e=0..7 (index algebra == old swizzled LDS path)
    const float* Wc0 = W + (2 * w) * 16 + l15;
    const float* Wc1 = Wc0 + 16;
    short8v af00 = packAfrag(Wc0 + (  0 + 8 * q) * 128);
    short8v af01 = packAfrag(Wc0 + ( 32 + 8 * q) * 128);
    short8v af02 = packAfrag(Wc0 + ( 64 + 8 * q) * 128);
    short8v af03 = packAfrag(Wc0 + ( 96 + 8 * q) * 128);
    short8v af10 = packAfrag(Wc1 + (  0 + 8 * q) * 128);
    short8v af11 = packAfrag(Wc1 + ( 32 + 8 * q) * 128);
    short8v af12 = packAfrag(Wc1 + ( 64 + 8 * q) * 128);
    short8v af13 = packAfrag(Wc1 + ( 96 + 8 * q) * 128);

    float hstep = (tt[1] - tt[0]) * 0.03125f;
    float c21 = hstep * 0.2f;
    float c31 = hstep * 0.075f,               c32 = hstep * 0.225f;
    float c41 = hstep * 0.9777777777777777f,  c42 = hstep * -3.7333333333333334f,
          c43 = hstep * 3.5555555555555554f;
    float c51 = hstep * 2.9525986892242035f,  c52 = hstep * -11.595793324188385f,
          c53 = hstep * 9.822892851699436f,   c54 = hstep * -0.2908093278463649f;
    float c61 = hstep * 2.8462752525252526f,  c62 = hstep * -10.757575757575758f,
          c63 = hstep * 8.906422717743473f,   c64 = hstep * 0.2784090909090909f,
          c65 = hstep * -0.2735313036020583f;
    float d1 = hstep * 0.09114583333333333f,  d3 = hstep * 0.44923629829290207f,
          d4 = hstep * 0.6510416666666666f,   d5 = hstep * -0.322376179245283f,
          d6 = hstep * 0.13095238095238096f;

    // ODE bias (b_ode) for my 2 col-groups
    f32x4 bias0 = *(const f32x4*)&bb[(2 * w)     * 16 + q * 4];
    f32x4 bias1 = *(const f32x4*)&bb[(2 * w + 1) * 16 + q * 4];

    long grow = (long)blockIdx.x * 16 + l15;
    bool ok = grow < nrows;

    // ---- gather prologue: y0 for node `grow`, my 8 cols ----
    const float* hwA  = (w < 2) ? hwp   : hwn;
    const int*   srcA = (w < 2) ? srcp  : srcn;
    const int*   rpA  = (w < 2) ? rpp   : rpn;
    const float* dvA  = (w < 2) ? dinvp : dinvn;
    const float* gbA  = (w < 2) ? gbp   : gbn;
    int col0 = ((2 * w) & 3) * 16 + q * 4;   // hw-row col of group 2w
    int col1 = col0 + 16;                    // hw-row col of group 2w+1

    f32x4 y[2];
    y[0] = (f32x4){0.0f, 0.0f, 0.0f, 0.0f};
    y[1] = (f32x4){0.0f, 0.0f, 0.0f, 0.0f};
    if (ok) {
        int dnode = (int)grow;
        int beg = rpA[dnode], end = rpA[dnode + 1];
        for (int i = beg; i < end; ++i) {
            int a = srcA[i];
            float dva = dvA[a];
            f32x4 h0 = *(const f32x4*)&hwA[(long)a * 64 + col0];
            f32x4 h1 = *(const f32x4*)&hwA[(long)a * 64 + col1];
            #pragma unroll
            for (int r = 0; r < 4; ++r) { y[0][r] += dva * h0[r]; y[1][r] += dva * h1[r]; }
        }
        float dvd = dvA[dnode];
        f32x4 h0 = *(const f32x4*)&hwA[(long)dnode * 64 + col0];
        f32x4 h1 = *(const f32x4*)&hwA[(long)dnode * 64 + col1];
        f32x4 gb0 = *(const f32x4*)&gbA[col0];
        f32x4 gb1 = *(const f32x4*)&gbA[col1];
        #pragma unroll
        for (int r = 0; r < 4; ++r) {
            y[0][r] = dvd * (y[0][r] + dvd * h0[r]) + gb0[r];
            y[1][r] = dvd * (y[1][r] + dvd * h1[r]) + gb1[r];
        }
    }

    char* bufA = smem;          // 16 rows x 256B = 4KB
    char* bufB = smem + 4096;   // double buffer

    f32x4 kp1[2], kp2[2], kp3[2], kp4[2], kp5[2];

    #pragma unroll 1
    for (int step = 0; step < 32; ++step) {
        ODE_STAGE(bufA, YI1, CONS1);
        ODE_STAGE(bufB, YI2, CONS2);
        ODE_STAGE(bufA, YI3, CONS3);
        ODE_STAGE(bufB, YI4, CONS4);
        ODE_STAGE(bufA, YI5, CONS5);
        ODE_STAGE(bufB, YI6, CONS6);
    }

    if (ok) {
        *(f32x4*)&out[grow * 128 + (2 * w)     * 16 + q * 4] = y[0];
        *(f32x4*)&out[grow * 128 + (2 * w + 1) * 16 + q * 4] = y[1];
    }
}

// ---------------------------------------------------------------------------

extern "C" void kernel_launch(void* const* d_in, const int* in_sizes, int n_in,
                              void* d_out, int out_size, void* d_ws, size_t ws_size,
                              hipStream_t stream) {
    const float* x     = (const float*)d_in[0];
    const int*   pei   = (const int*)d_in[1];
    const int*   nei   = (const int*)d_in[2];
    const float* t     = (const float*)d_in[3];
    const float* W_enc = (const float*)d_in[4];
    const float* b_enc = (const float*)d_in[5];
    const float* W_pos = (const float*)d_in[6];
    const float* b_pos = (const float*)d_in[7];
    const float* W_neg = (const float*)d_in[8];
    const float* b_neg = (const float*)d_in[9];
    const float* W_ode = (const float*)d_in[10];
    const float* b_ode = (const float*)d_in[11];

    int n  = in_sizes[0] / 128;   // 50000 nodes
    int nE = in_sizes[1] / 2;     // 800000 edges

    // ws layout (NO aliasing with d_out):
    //   floats hwp[n*64], hwn[n*64]  (25.6MB)
    //   ints   srcp[nE], srcn[nE], cntp[n], cntn[n], rpp[n+1], rpn[n+1] (7.2MB)
    //   floats dinvp[n], dinvn[n]    (0.4MB)           total ~33.2MB
    float* hwp = (float*)d_ws;
    float* hwn = hwp + (long)n * 64;
    int* srcp = (int*)(hwn + (long)n * 64);
    int* srcn = srcp + nE;
    int* cntp = srcn + nE;
    int* cntn = cntp + n;            // cntp,cntn contiguous -> single memset
    int* rpp  = cntn + n;
    int* rpn  = rpp + (n + 1);
    float* dinvp = (float*)(rpn + (n + 1));
    float* dinvn = dinvp + n;

    const int* psrc = pei;       const int* pdst = pei + nE;
    const int* nsrc = nei;       const int* ndst = nei + nE;

    int nbE = (nE + 255) / 256;
    int nbR = (n + 3) / 4;

    hipMemsetAsync(cntp, 0, (size_t)(2 * n) * sizeof(int), stream);
    prep_kernel     <<<nbE + nbR, 256, 0, stream>>>(x, W_enc, b_enc, W_pos, W_neg,
                                                    hwp, hwn, pdst, ndst, cntp, cntn,
                                                    n, nE, nbE);
    scan_kernel     <<<2, 1024, 0, stream>>>(cntp, cntn, rpp, rpn, dinvp, dinvn, n);
    fill_both_kernel<<<2 * nbE, 256, 0, stream>>>(psrc, pdst, nsrc, ndst, rpp, rpn,
                                                  cntp, cntn, srcp, srcn, nE, nbE);
    ode_mfma_kernel <<<(n + 15) / 16, 256, 0, stream>>>(hwp, hwn, srcp, srcn, rpp, rpn,
                                                        dinvp, dinvn, b_pos, b_neg,
                                                        (float*)d_out, W_ode, b_ode, t, n);
}